// Round 5
// baseline (319.614 us; speedup 1.0000x reference)
//
#include <hip/hip_runtime.h>
#include <math.h>

#define N_NODES 100000
#define N_PART  5000
#define N_EDGES 1000000
#define D_NODE  128
#define D_PART  128
#define D_ATT   20
#define NBLK    128   // counting-sort blocks
#define EPB     ((N_EDGES + NBLK - 1) / NBLK)
#define TPV6    8     // particles per block in gru_fused_v7 / query_gemm

__device__ __forceinline__ float sigmoid_(float x) { return 1.f / (1.f + __expf(-x)); }
__device__ __forceinline__ float tanh_(float x)    { return 1.f - 2.f / (__expf(2.f * x) + 1.f); }

// 16-FMA body for the 512-wide GRU GEMM (4 k-rows x 4 cols x 4 particles)
__device__ __forceinline__ void gru_body(float4 acc[4],
    float4 w0, float4 w1, float4 w2, float4 w3,
    float4 x0, float4 x1, float4 x2, float4 x3)
{
    acc[0].x += x0.x * w0.x + x0.y * w1.x + x0.z * w2.x + x0.w * w3.x;
    acc[0].y += x0.x * w0.y + x0.y * w1.y + x0.z * w2.y + x0.w * w3.y;
    acc[0].z += x0.x * w0.z + x0.y * w1.z + x0.z * w2.z + x0.w * w3.z;
    acc[0].w += x0.x * w0.w + x0.y * w1.w + x0.z * w2.w + x0.w * w3.w;
    acc[1].x += x1.x * w0.x + x1.y * w1.x + x1.z * w2.x + x1.w * w3.x;
    acc[1].y += x1.x * w0.y + x1.y * w1.y + x1.z * w2.y + x1.w * w3.y;
    acc[1].z += x1.x * w0.z + x1.y * w1.z + x1.z * w2.z + x1.w * w3.z;
    acc[1].w += x1.x * w0.w + x1.y * w1.w + x1.z * w2.w + x1.w * w3.w;
    acc[2].x += x2.x * w0.x + x2.y * w1.x + x2.z * w2.x + x2.w * w3.x;
    acc[2].y += x2.x * w0.y + x2.y * w1.y + x2.z * w2.y + x2.w * w3.y;
    acc[2].z += x2.x * w0.z + x2.y * w1.z + x2.z * w2.z + x2.w * w3.z;
    acc[2].w += x2.x * w0.w + x2.y * w1.w + x2.z * w2.w + x2.w * w3.w;
    acc[3].x += x3.x * w0.x + x3.y * w1.x + x3.z * w2.x + x3.w * w3.x;
    acc[3].y += x3.x * w0.y + x3.y * w1.y + x3.z * w2.y + x3.w * w3.y;
    acc[3].z += x3.x * w0.z + x3.y * w1.z + x3.z * w2.z + x3.w * w3.z;
    acc[3].w += x3.x * w0.w + x3.y * w1.w + x3.z * w2.w + x3.w * w3.w;
}

// 4-col x 4-k body for the 128-wide query GEMM (one particle per thread)
__device__ __forceinline__ void q_body(float4& acc,
    float4 w0, float4 w1, float4 w2, float4 w3, float4 x)
{
    acc.x += x.x * w0.x + x.y * w1.x + x.z * w2.x + x.w * w3.x;
    acc.y += x.x * w0.y + x.y * w1.y + x.z * w2.y + x.w * w3.y;
    acc.z += x.x * w0.z + x.y * w1.z + x.z * w2.z + x.w * w3.z;
    acc.w += x.x * w0.w + x.y * w1.w + x.z * w2.w + x.w * w3.w;
}

// ---------------------------------------------------------------------------
// P0: build combined GRU weight matrix Wbig[256][512], GATE-INTERLEAVED:
//   new column jn = c*4 + g  (c in [0,128), g in {0:r, 1:z, 2:i_n, 3:h_n})
// ---------------------------------------------------------------------------
__global__ __launch_bounds__(256) void build_wbig_kernel(
    const float* __restrict__ valW, const float* __restrict__ Wih,
    const float* __restrict__ Whh, float* __restrict__ Wbig)
{
    int idx = blockIdx.x * 256 + threadIdx.x;   // 131072 total
    int k = idx >> 9;
    int jn = idx & 511;
    int j = (jn & 3) * 128 + (jn >> 2);         // old column
    float v = 0.f;
    if (k < 128) {
        if (j < 384) {
            float acc = 0.f;
            #pragma unroll 8
            for (int m = 0; m < 128; m++)
                acc += valW[k * 128 + m] * Wih[j * 128 + m];
            v = acc;
        }
    } else {
        int kp = k - 128;
        if (j < 256)       v = Whh[j * 128 + kp];
        else if (j >= 384) v = Whh[(j - 128) * 128 + kp];
    }
    Wbig[k * 512 + jn] = v;
}

// ---------------------------------------------------------------------------
// P0b (merged small builds), one grid of 132 blocks:
//  [0,32768):      Wq[k][j]  = sum_a qW[k][a]*keyW[j][a]   (k<256, j<128)
//  [32768,33024):  qoffW[k]  = sum_a qW[k][a]*keyb[a]
//  [33024,33152):  cqk[j]    = sum_a keyW[j][a]*qb[a]
//  33152:          cqoff     = sum_a keyb[a]*qb[a]
//  [33280,33664):  bvec[c]   = sum_m valb[m]*Wih[c][m]     (c<384)
// ---------------------------------------------------------------------------
__global__ __launch_bounds__(256) void build_small_kernel(
    const float* __restrict__ qW, const float* __restrict__ qb,
    const float* __restrict__ keyW, const float* __restrict__ keyb,
    const float* __restrict__ valb, const float* __restrict__ Wih,
    float* __restrict__ Wq, float* __restrict__ qoffW,
    float* __restrict__ cqk, float* __restrict__ cqoff,
    float* __restrict__ bvec)
{
    int jx = blockIdx.x * 256 + threadIdx.x;
    if (jx < 32768) {
        int k = jx >> 7, j = jx & 127;
        float acc = 0.f;
        #pragma unroll
        for (int a = 0; a < D_ATT; a++) acc += qW[k * D_ATT + a] * keyW[j * D_ATT + a];
        Wq[k * 128 + j] = acc;
    } else if (jx < 33024) {
        int k = jx - 32768;
        float acc = 0.f;
        #pragma unroll
        for (int a = 0; a < D_ATT; a++) acc += qW[k * D_ATT + a] * keyb[a];
        qoffW[k] = acc;
    } else if (jx < 33152) {
        int j = jx - 33024;
        float acc = 0.f;
        #pragma unroll
        for (int a = 0; a < D_ATT; a++) acc += keyW[j * D_ATT + a] * qb[a];
        cqk[j] = acc;
    } else if (jx == 33152) {
        float acc = 0.f;
        #pragma unroll
        for (int a = 0; a < D_ATT; a++) acc += keyb[a] * qb[a];
        cqoff[0] = acc;
    } else if (jx >= 33280 && jx < 33664) {
        int c = jx - 33280;
        float acc = 0.f;
        #pragma unroll 8
        for (int m = 0; m < 128; m++) acc += valb[m] * Wih[c * 128 + m];
        bvec[c] = acc;
    }
}

// ---------------------------------------------------------------------------
// K1 v2: query-fold GEMM  qk[p][j] = cqk[j] + [ph|gr][p] @ Wq[:,j]
//        qoff[p] = cqoff + [ph|gr][p] . qoffW
// v6-style barrier-free GEMM: 8 particles/block, 625 blocks, 256 threads,
// thread = (particle pl = t>>5, column-quad cq = (t&31)*4), 2-body pipeline.
// Replaces query_qk_kernel whose 20-thread serial 256-iter loop was the
// suspected ~30us hidden cost.
// ---------------------------------------------------------------------------
__global__ __launch_bounds__(256) void query_gemm_kernel(
    const float* __restrict__ ph, const float* __restrict__ gr,
    const float* __restrict__ Wq, const float* __restrict__ qoffW,
    const float* __restrict__ cqk, const float* __restrict__ cqoff,
    float* __restrict__ qk, float* __restrict__ qoff)
{
    __shared__ float s_in[TPV6][256];   // [ph | gr] per particle (8192 B)
    int t = threadIdx.x;
    int pbase = blockIdx.x * TPV6;

    for (int f = t; f < TPV6 * 64; f += 256) {
        int pl = f >> 6, r = f & 63;
        int c4 = r * 4;
        int p = pbase + pl;
        float4 v;
        if (c4 < 128) v = *(const float4*)(ph + (size_t)p * 128 + c4);
        else          v = *(const float4*)(gr + (size_t)p * 128 + (c4 - 128));
        *(float4*)&s_in[pl][c4] = v;
    }
    __syncthreads();

    int cq = (t & 31) * 4;   // column quad
    int pl = t >> 5;         // particle 0..7
    const float* wp = Wq + cq;

    float4 acc = {0.f, 0.f, 0.f, 0.f};
    // A = rows k..k+3, B = rows k+4..k+7
    float4 wa0 = *(const float4*)(wp);
    float4 wa1 = *(const float4*)(wp + 128);
    float4 wa2 = *(const float4*)(wp + 256);
    float4 wa3 = *(const float4*)(wp + 384);
    float4 xa  = *(const float4*)&s_in[pl][0];
    float4 wb0 = *(const float4*)(wp + 512);
    float4 wb1 = *(const float4*)(wp + 640);
    float4 wb2 = *(const float4*)(wp + 768);
    float4 wb3 = *(const float4*)(wp + 896);
    float4 xb  = *(const float4*)&s_in[pl][4];

    for (int k = 0; k < 256; k += 8) {
        float4 ca0 = wa0, ca1 = wa1, ca2 = wa2, ca3 = wa3, cxa = xa;
        if (k + 8 < 256) {
            const float* wn = wp + (size_t)(k + 8) * 128;
            wa0 = *(const float4*)(wn);
            wa1 = *(const float4*)(wn + 128);
            wa2 = *(const float4*)(wn + 256);
            wa3 = *(const float4*)(wn + 384);
            xa  = *(const float4*)&s_in[pl][k + 8];
        }
        q_body(acc, ca0, ca1, ca2, ca3, cxa);
        float4 cb0 = wb0, cb1 = wb1, cb2 = wb2, cb3 = wb3, cxb = xb;
        if (k + 12 < 256) {
            const float* wn = wp + (size_t)(k + 12) * 128;
            wb0 = *(const float4*)(wn);
            wb1 = *(const float4*)(wn + 128);
            wb2 = *(const float4*)(wn + 256);
            wb3 = *(const float4*)(wn + 384);
            xb  = *(const float4*)&s_in[pl][k + 12];
        }
        q_body(acc, cb0, cb1, cb2, cb3, cxb);
    }

    float4 cst = *(const float4*)(cqk + cq);
    float4 o;
    o.x = cst.x + acc.x; o.y = cst.y + acc.y;
    o.z = cst.z + acc.z; o.w = cst.w + acc.w;
    *(float4*)(qk + (size_t)(pbase + pl) * 128 + cq) = o;

    // qoff: wave wv handles particles 2*wv, 2*wv+1 (s_in is read-only here)
    int wv = t >> 6, l = t & 63;
    float co = cqoff[0];
    #pragma unroll
    for (int i = 0; i < 2; i++) {
        int pp = wv * 2 + i;
        float s = s_in[pp][l]       * qoffW[l]
                + s_in[pp][l + 64]  * qoffW[l + 64]
                + s_in[pp][l + 128] * qoffW[l + 128]
                + s_in[pp][l + 192] * qoffW[l + 192];
        #pragma unroll
        for (int off = 1; off <= 32; off <<= 1) s += __shfl_xor(s, off, 64);
        if (l == 0) qoff[pbase + pp] = co + s;
    }
}

// ---------------------------------------------------------------------------
// K2a: per-block LDS histogram of dst
// ---------------------------------------------------------------------------
__global__ __launch_bounds__(256) void block_hist_kernel(
    const int* __restrict__ dst, int* __restrict__ blockhist)
{
    __shared__ int h[N_PART];
    int b = blockIdx.x;
    for (int i = threadIdx.x; i < N_PART; i += 256) h[i] = 0;
    __syncthreads();
    int beg = b * EPB, end = min(beg + EPB, N_EDGES);
    for (int e = beg + threadIdx.x; e < end; e += 256)
        atomicAdd(&h[dst[e]], 1);
    __syncthreads();
    for (int i = threadIdx.x; i < N_PART; i += 256)
        blockhist[(size_t)b * N_PART + i] = h[i];
}

// ---------------------------------------------------------------------------
// K2b: per-dst column scan over blocks
// ---------------------------------------------------------------------------
__global__ __launch_bounds__(256) void colscan_kernel(
    int* __restrict__ blockhist, int* __restrict__ totals)
{
    int i = blockIdx.x * 256 + threadIdx.x;
    if (i >= N_PART) return;
    int run = 0;
    for (int b = 0; b < NBLK; b++) {
        size_t idx = (size_t)b * N_PART + i;
        int v = blockhist[idx];
        blockhist[idx] = run;
        run += v;
    }
    totals[i] = run;
}

// ---------------------------------------------------------------------------
// K2c: exclusive scan of totals[5000] -> offsets[5001]
// ---------------------------------------------------------------------------
__global__ __launch_bounds__(256) void scan_kernel(
    const int* __restrict__ totals, int* __restrict__ offsets)
{
    __shared__ int ss[256];
    int t = threadIdx.x;
    const int CH = 20;
    int beg = t * CH;
    int end = min(beg + CH, N_PART);
    int lsum = 0;
    for (int i = beg; i < end; i++) lsum += totals[i];
    ss[t] = lsum;
    __syncthreads();
    for (int off = 1; off < 256; off <<= 1) {
        int v = (t >= off) ? ss[t - off] : 0;
        __syncthreads();
        ss[t] += v;
        __syncthreads();
    }
    int base = ss[t] - lsum;
    for (int i = beg; i < end; i++) {
        offsets[i] = base;
        base += totals[i];
    }
    if (t == 0) offsets[N_PART] = N_EDGES;
}

// ---------------------------------------------------------------------------
// K2d: scatter src into dst-sorted order using per-block LDS cursors
// ---------------------------------------------------------------------------
__global__ __launch_bounds__(256) void scatter_sorted_kernel(
    const int* __restrict__ src, const int* __restrict__ dst,
    const int* __restrict__ offsets, const int* __restrict__ blockhist,
    int* __restrict__ ssrc)
{
    __shared__ int cur[N_PART];
    int b = blockIdx.x;
    for (int i = threadIdx.x; i < N_PART; i += 256)
        cur[i] = offsets[i] + blockhist[(size_t)b * N_PART + i];
    __syncthreads();
    int beg = b * EPB, end = min(beg + EPB, N_EDGES);
    for (int e = beg + threadIdx.x; e < end; e += 256) {
        int d = dst[e];
        int pos = atomicAdd(&cur[d], 1);
        ssrc[pos] = src[e];
    }
}

// ---------------------------------------------------------------------------
// K3: per-dst edge accumulation. Half-wave (32 lanes x float4) per edge.
// Round-0 form (gather-service-bound: rounds 1/4 ledger shows deeper MLP
// is neutral; leave as-is).
// ---------------------------------------------------------------------------
__global__ __launch_bounds__(256) void edge_agg_kernel(
    const float* __restrict__ nodes, const float* __restrict__ qk,
    const float* __restrict__ qoff,
    const int* __restrict__ offsets, const int* __restrict__ ssrc,
    float* __restrict__ agg, float* __restrict__ att_sum)
{
    const float norm = 0.22360679774997896f;  // 1/sqrt(20)
    int p = blockIdx.x;
    int tid = threadIdx.x;
    int lane = tid & 63;
    int wave = tid >> 6;
    int half = lane >> 5;
    int colq = (lane & 31) * 4;

    const float4 q = *(const float4*)(qk + (size_t)p * 128 + colq);
    float qo = qoff[p];
    int beg = offsets[p], end = offsets[p + 1];
    int n = end - beg;
    int np = (n + 1) >> 1;   // total pairs (last may be partial)
    int npfull = n >> 1;     // pairs with both edges present

    float4 a = {0.f, 0.f, 0.f, 0.f};
    float asum = 0.f;

    int pi = wave;
    for (; pi + 12 < npfull; pi += 16) {
        int e0 = beg + 2 * pi + half;
        int s0 = ssrc[e0];
        int s1 = ssrc[e0 + 8];
        int s2 = ssrc[e0 + 16];
        int s3 = ssrc[e0 + 24];
        float4 x0 = *(const float4*)(nodes + (size_t)s0 * 128 + colq);
        float4 x1 = *(const float4*)(nodes + (size_t)s1 * 128 + colq);
        float4 x2 = *(const float4*)(nodes + (size_t)s2 * 128 + colq);
        float4 x3 = *(const float4*)(nodes + (size_t)s3 * 128 + colq);
        float d0 = x0.x * q.x + x0.y * q.y + x0.z * q.z + x0.w * q.w;
        float d1 = x1.x * q.x + x1.y * q.y + x1.z * q.z + x1.w * q.w;
        float d2 = x2.x * q.x + x2.y * q.y + x2.z * q.z + x2.w * q.w;
        float d3 = x3.x * q.x + x3.y * q.y + x3.z * q.z + x3.w * q.w;
        #pragma unroll
        for (int off = 1; off <= 16; off <<= 1) {
            d0 += __shfl_xor(d0, off, 64);
            d1 += __shfl_xor(d1, off, 64);
            d2 += __shfl_xor(d2, off, 64);
            d3 += __shfl_xor(d3, off, 64);
        }
        float t0 = (d0 + qo) * norm;
        float t1 = (d1 + qo) * norm;
        float t2 = (d2 + qo) * norm;
        float t3 = (d3 + qo) * norm;
        a.x += t0 * x0.x + t1 * x1.x + t2 * x2.x + t3 * x3.x;
        a.y += t0 * x0.y + t1 * x1.y + t2 * x2.y + t3 * x3.y;
        a.z += t0 * x0.z + t1 * x1.z + t2 * x2.z + t3 * x3.z;
        a.w += t0 * x0.w + t1 * x1.w + t2 * x2.w + t3 * x3.w;
        asum += t0 + t1 + t2 + t3;
    }
    for (; pi < np; pi += 4) {
        int e0 = beg + 2 * pi;
        bool has1 = (e0 + 1 < end);
        int s0 = ssrc[e0];
        int s1 = has1 ? ssrc[e0 + 1] : s0;
        int s = half ? s1 : s0;
        float4 x = *(const float4*)(nodes + (size_t)s * 128 + colq);
        float d = x.x * q.x + x.y * q.y + x.z * q.z + x.w * q.w;
        #pragma unroll
        for (int off = 1; off <= 16; off <<= 1) d += __shfl_xor(d, off, 64);
        float att = (d + qo) * norm;
        if (half && !has1) att = 0.f;
        a.x += att * x.x; a.y += att * x.y; a.z += att * x.z; a.w += att * x.w;
        asum += att;
    }

    a.x += __shfl_xor(a.x, 32, 64);
    a.y += __shfl_xor(a.y, 32, 64);
    a.z += __shfl_xor(a.z, 32, 64);
    a.w += __shfl_xor(a.w, 32, 64);
    asum += __shfl_xor(asum, 32, 64);

    __shared__ float s_acc[4][128];
    __shared__ float s_as[4];
    if (lane < 32) {
        *(float4*)&s_acc[wave][colq] = a;
        if (lane == 0) s_as[wave] = asum;
    }
    __syncthreads();

    if (tid < 128) {
        float v = s_acc[0][tid] + s_acc[1][tid] + s_acc[2][tid] + s_acc[3][tid];
        agg[(size_t)p * 128 + tid] = v;
        if (tid == 0) att_sum[p] = s_as[0] + s_as[1] + s_as[2] + s_as[3];
    }
}

// ---------------------------------------------------------------------------
// K4 v7: v6 + 2-body-deep prefetch (A/B interleaved pipelines).
// v6 measured ~53us vs ~8us VALU floor: 1-deep covers ~128cy of ~250cy L2
// latency; 2-deep covers ~256cy. VGPR budget ~125 (watch for spill).
// ---------------------------------------------------------------------------
__global__ __launch_bounds__(256) void gru_fused_v7(
    const float* __restrict__ agg, const float* __restrict__ att_sum,
    const float* __restrict__ ph,
    const float* __restrict__ Wbig, const float* __restrict__ bvec,
    const float* __restrict__ bih, const float* __restrict__ bhh,
    const float* __restrict__ lng, const float* __restrict__ lnb,
    const float* __restrict__ W1, const float* __restrict__ b1,
    const float* __restrict__ W2, const float* __restrict__ b2,
    float* __restrict__ out)
{
    __shared__ float s_in[TPV6][256];    // [agg | h] per particle (8192 B)
    __shared__ float s_ln[TPV6][128];    //                        (4096 B)
    __shared__ float s_hid[TPV6][64];    //                        (2048 B)

    int t = threadIdx.x;
    int pbase = blockIdx.x * TPV6;

    for (int f = t; f < TPV6 * 64; f += 256) {
        int pl = f >> 6, r = f & 63;
        int c4 = r * 4;
        int p = pbase + pl;
        float4 v;
        if (c4 < 128) v = *(const float4*)(agg + (size_t)p * 128 + c4);
        else          v = *(const float4*)(ph + (size_t)p * 128 + (c4 - 128));
        *(float4*)&s_in[pl][c4] = v;
    }

    int c  = t & 127;        // output column 0..127
    int j4 = c * 4;          // interleaved column base in Wbig
    int pg = t >> 7;         // particle group 0/1 -> particles pg*4 .. pg*4+3
    float4 cb, bv;
    cb.x = bih[c]       + bhh[c];        bv.x = bvec[c];        // r
    cb.y = bih[128 + c] + bhh[128 + c];  bv.y = bvec[128 + c];  // z
    cb.z = bih[256 + c];                 bv.z = bvec[256 + c];  // i_n
    cb.w = bhh[256 + c];                 bv.w = 0.f;            // h_n
    float4 acc[4];
    #pragma unroll
    for (int i = 0; i < 4; i++) {
        float as = att_sum[pbase + pg * 4 + i];
        acc[i].x = cb.x + as * bv.x;
        acc[i].y = cb.y + as * bv.y;
        acc[i].z = cb.z + as * bv.z;
        acc[i].w = cb.w + as * bv.w;
    }
    __syncthreads();

    // ---- K-loop: barrier-free, w from L2-resident global, 2-body pipeline
    const float* wp = Wbig + j4;
    float4 wa0 = *(const float4*)(wp);
    float4 wa1 = *(const float4*)(wp + 512);
    float4 wa2 = *(const float4*)(wp + 1024);
    float4 wa3 = *(const float4*)(wp + 1536);
    float4 xa0 = *(const float4*)&s_in[pg * 4 + 0][0];
    float4 xa1 = *(const float4*)&s_in[pg * 4 + 1][0];
    float4 xa2 = *(const float4*)&s_in[pg * 4 + 2][0];
    float4 xa3 = *(const float4*)&s_in[pg * 4 + 3][0];
    float4 wb0 = *(const float4*)(wp + 2048);
    float4 wb1 = *(const float4*)(wp + 2560);
    float4 wb2 = *(const float4*)(wp + 3072);
    float4 wb3 = *(const float4*)(wp + 3584);
    float4 xb0 = *(const float4*)&s_in[pg * 4 + 0][4];
    float4 xb1 = *(const float4*)&s_in[pg * 4 + 1][4];
    float4 xb2 = *(const float4*)&s_in[pg * 4 + 2][4];
    float4 xb3 = *(const float4*)&s_in[pg * 4 + 3][4];

    for (int k = 0; k < 256; k += 8) {
        float4 ca0 = wa0, ca1 = wa1, ca2 = wa2, ca3 = wa3;
        float4 cx0 = xa0, cx1 = xa1, cx2 = xa2, cx3 = xa3;
        if (k + 8 < 256) {
            const float* wn = wp + (size_t)(k + 8) * 512;
            wa0 = *(const float4*)(wn);
            wa1 = *(const float4*)(wn + 512);
            wa2 = *(const float4*)(wn + 1024);
            wa3 = *(const float4*)(wn + 1536);
            xa0 = *(const float4*)&s_in[pg * 4 + 0][k + 8];
            xa1 = *(const float4*)&s_in[pg * 4 + 1][k + 8];
            xa2 = *(const float4*)&s_in[pg * 4 + 2][k + 8];
            xa3 = *(const float4*)&s_in[pg * 4 + 3][k + 8];
        }
        gru_body(acc, ca0, ca1, ca2, ca3, cx0, cx1, cx2, cx3);
        float4 cb0 = wb0, cb1 = wb1, cb2 = wb2, cb3 = wb3;
        float4 dx0 = xb0, dx1 = xb1, dx2 = xb2, dx3 = xb3;
        if (k + 12 < 256) {
            const float* wn = wp + (size_t)(k + 12) * 512;
            wb0 = *(const float4*)(wn);
            wb1 = *(const float4*)(wn + 512);
            wb2 = *(const float4*)(wn + 1024);
            wb3 = *(const float4*)(wn + 1536);
            xb0 = *(const float4*)&s_in[pg * 4 + 0][k + 12];
            xb1 = *(const float4*)&s_in[pg * 4 + 1][k + 12];
            xb2 = *(const float4*)&s_in[pg * 4 + 2][k + 12];
            xb3 = *(const float4*)&s_in[pg * 4 + 3][k + 12];
        }
        gru_body(acc, cb0, cb1, cb2, cb3, dx0, dx1, dx2, dx3);
    }

    // ---- gates entirely in registers: hn = (1-z)*n + z*h
    #pragma unroll
    for (int i = 0; i < 4; i++) {
        int pl = pg * 4 + i;
        float r = sigmoid_(acc[i].x);
        float z = sigmoid_(acc[i].y);
        float n = tanh_(acc[i].z + r * acc[i].w);
        float h = s_in[pl][128 + c];
        s_ln[pl][c] = (1.f - z) * n + z * h;
    }
    __syncthreads();

    // ---- LayerNorm per particle
    {
        int wv = t >> 6, l = t & 63;
        for (int pl = wv; pl < TPV6; pl += 4) {
            float v0 = s_ln[pl][l * 2], v1 = s_ln[pl][l * 2 + 1];
            float sum = v0 + v1, sq = v0 * v0 + v1 * v1;
            #pragma unroll
            for (int off = 1; off <= 32; off <<= 1) {
                sum += __shfl_xor(sum, off, 64);
                sq  += __shfl_xor(sq, off, 64);
            }
            float mu = sum * (1.f / 128.f);
            float var = sq * (1.f / 128.f) - mu * mu;
            float rstd = rsqrtf(var + 1e-5f);
            s_ln[pl][l * 2]     = (v0 - mu) * rstd * lng[l * 2] + lnb[l * 2];
            s_ln[pl][l * 2 + 1] = (v1 - mu) * rstd * lng[l * 2 + 1] + lnb[l * 2 + 1];
        }
    }
    __syncthreads();

    // ---- MLP hidden (8*64 = 512 outputs)
    for (int idx = t; idx < TPV6 * 64; idx += 256) {
        int pl = idx >> 6, u = idx & 63;
        float a0 = b1[u];
        #pragma unroll 4
        for (int k = 0; k < 128; k++) a0 += s_ln[pl][k] * W1[k * 64 + u];
        s_hid[pl][u] = fmaxf(a0, 0.f);
    }
    __syncthreads();

    // ---- MLP out + residual (256 column-quads)
    for (int idx = t; idx < TPV6 * 32; idx += 256) {
        int pl = idx >> 5, qd = idx & 31;
        int c4 = qd * 4;
        float4 o = *(const float4*)(b2 + c4);
        #pragma unroll 4
        for (int u = 0; u < 64; u++) {
            float av = s_hid[pl][u];
            float4 w = *(const float4*)(W2 + u * 128 + c4);
            o.x += av * w.x; o.y += av * w.y; o.z += av * w.z; o.w += av * w.w;
        }
        float4 h4 = *(const float4*)&s_in[pl][128 + c4];
        float4 res;
        res.x = h4.x + o.x; res.y = h4.y + o.y;
        res.z = h4.z + o.z; res.w = h4.w + o.w;
        *(float4*)(out + (size_t)(pbase + pl) * 128 + c4) = res;
    }
}

// ---------------------------------------------------------------------------
extern "C" void kernel_launch(void* const* d_in, const int* in_sizes, int n_in,
                              void* d_out, int out_size, void* d_ws, size_t ws_size,
                              hipStream_t stream) {
    const float* nodes = (const float*)d_in[0];
    const float* ph    = (const float*)d_in[1];
    const float* gr    = (const float*)d_in[2];
    const int*   src   = (const int*)d_in[3];
    const int*   dst   = (const int*)d_in[4];
    const float* keyW  = (const float*)d_in[5];
    const float* keyb  = (const float*)d_in[6];
    const float* valW  = (const float*)d_in[7];
    const float* valb  = (const float*)d_in[8];
    const float* qW    = (const float*)d_in[9];
    const float* qb    = (const float*)d_in[10];
    const float* Wih   = (const float*)d_in[11];
    const float* Whh   = (const float*)d_in[12];
    const float* bih   = (const float*)d_in[13];
    const float* bhh   = (const float*)d_in[14];
    const float* lng   = (const float*)d_in[15];
    const float* lnb   = (const float*)d_in[16];
    const float* W1    = (const float*)d_in[17];
    const float* b1    = (const float*)d_in[18];
    const float* W2    = (const float*)d_in[19];
    const float* b2    = (const float*)d_in[20];
    float* out = (float*)d_out;

    // workspace layout
    float* ws_f      = (float*)d_ws;
    float* qk        = ws_f;                     // 640,000
    float* qoff      = qk + 640000;              // 5,008
    float* agg       = qoff + 5008;              // 640,000
    float* att_sum   = agg + 640000;             // 5,008
    int*   totals    = (int*)(att_sum + 5008);   // 5,008
    int*   offsets   = totals + 5008;            // 5,008
    int*   blockhist = offsets + 5008;           // NBLK*5000
    int*   ssrc      = blockhist + (size_t)NBLK * N_PART;  // 1,000,000
    float* Wbig      = (float*)(ssrc + 1000000); // 131,072
    float* bvec      = Wbig + 131072;            // 512 (384 used)
    float* Wq        = bvec + 512;               // 32,768
    float* qoffW     = Wq + 32768;               // 256
    float* cqk       = qoffW + 256;              // 128
    float* cqoff     = cqk + 128;                // 16

    build_wbig_kernel<<<512, 256, 0, stream>>>(valW, Wih, Whh, Wbig);
    build_small_kernel<<<132, 256, 0, stream>>>(qW, qb, keyW, keyb, valb, Wih,
                                                Wq, qoffW, cqk, cqoff, bvec);
    query_gemm_kernel<<<N_PART / TPV6, 256, 0, stream>>>(
        ph, gr, Wq, qoffW, cqk, cqoff, qk, qoff);
    block_hist_kernel<<<NBLK, 256, 0, stream>>>(dst, blockhist);
    colscan_kernel<<<(N_PART + 255) / 256, 256, 0, stream>>>(blockhist, totals);
    scan_kernel<<<1, 256, 0, stream>>>(totals, offsets);
    scatter_sorted_kernel<<<NBLK, 256, 0, stream>>>(src, dst, offsets, blockhist, ssrc);
    edge_agg_kernel<<<N_PART, 256, 0, stream>>>(nodes, qk, qoff, offsets, ssrc, agg, att_sum);
    gru_fused_v7<<<N_PART / TPV6, 256, 0, stream>>>(
        agg, att_sum, ph, Wbig, bvec, bih, bhh, lng, lnb, W1, b1, W2, b2, out);
}

// Round 8
// 295.293 us; speedup vs baseline: 1.0824x; 1.0824x over previous
//
#include <hip/hip_runtime.h>
#include <math.h>

#define N_NODES 100000
#define N_PART  5000
#define N_EDGES 1000000
#define D_NODE  128
#define D_PART  128
#define D_ATT   20
#define NBLK    128   // counting-sort blocks
#define EPB     ((N_EDGES + NBLK - 1) / NBLK)
#define TPV6    8     // particles per block in gru_fused_v6 / query path
#define QBLKS   (N_PART / TPV6)   // 625 query blocks

__device__ __forceinline__ float sigmoid_(float x) { return 1.f / (1.f + __expf(-x)); }
__device__ __forceinline__ float tanh_(float x)    { return 1.f - 2.f / (__expf(2.f * x) + 1.f); }

// 16-FMA body for the 512-wide GRU GEMM (4 k-rows x 4 cols x 4 particles)
__device__ __forceinline__ void gru_body(float4 acc[4],
    float4 w0, float4 w1, float4 w2, float4 w3,
    float4 x0, float4 x1, float4 x2, float4 x3)
{
    acc[0].x += x0.x * w0.x + x0.y * w1.x + x0.z * w2.x + x0.w * w3.x;
    acc[0].y += x0.x * w0.y + x0.y * w1.y + x0.z * w2.y + x0.w * w3.y;
    acc[0].z += x0.x * w0.z + x0.y * w1.z + x0.z * w2.z + x0.w * w3.z;
    acc[0].w += x0.x * w0.w + x0.y * w1.w + x0.z * w2.w + x0.w * w3.w;
    acc[1].x += x1.x * w0.x + x1.y * w1.x + x1.z * w2.x + x1.w * w3.x;
    acc[1].y += x1.x * w0.y + x1.y * w1.y + x1.z * w2.y + x1.w * w3.y;
    acc[1].z += x1.x * w0.z + x1.y * w1.z + x1.z * w2.z + x1.w * w3.z;
    acc[1].w += x1.x * w0.w + x1.y * w1.w + x1.z * w2.w + x1.w * w3.w;
    acc[2].x += x2.x * w0.x + x2.y * w1.x + x2.z * w2.x + x2.w * w3.x;
    acc[2].y += x2.x * w0.y + x2.y * w1.y + x2.z * w2.y + x2.w * w3.y;
    acc[2].z += x2.x * w0.z + x2.y * w1.z + x2.z * w2.z + x2.w * w3.z;
    acc[2].w += x2.x * w0.w + x2.y * w1.w + x2.z * w2.w + x2.w * w3.w;
    acc[3].x += x3.x * w0.x + x3.y * w1.x + x3.z * w2.x + x3.w * w3.x;
    acc[3].y += x3.x * w0.y + x3.y * w1.y + x3.z * w2.y + x3.w * w3.y;
    acc[3].z += x3.x * w0.z + x3.y * w1.z + x3.z * w2.z + x3.w * w3.z;
    acc[3].w += x3.x * w0.w + x3.y * w1.w + x3.z * w2.w + x3.w * w3.w;
}

// 4-col x 4-k body for the 128-wide query GEMM (one particle per thread)
__device__ __forceinline__ void q_body(float4& acc,
    float4 w0, float4 w1, float4 w2, float4 w3, float4 x)
{
    acc.x += x.x * w0.x + x.y * w1.x + x.z * w2.x + x.w * w3.x;
    acc.y += x.x * w0.y + x.y * w1.y + x.z * w2.y + x.w * w3.y;
    acc.z += x.x * w0.z + x.y * w1.z + x.z * w2.z + x.w * w3.z;
    acc.w += x.x * w0.w + x.y * w1.w + x.z * w2.w + x.w * w3.w;
}

// ---------------------------------------------------------------------------
// L1 — fused front-end (772 blocks). Sections are disjoint (each is
// line-identical to a kernel that passed in rounds 4/5):
//   [0,512):   build_wbig   — Wbig[256][512], gate-interleaved
//   [512,644): build_small  — Wq / qoffW / cqk / cqoff / bvec
//   [644,772): block_hist   — per-block LDS histogram of dst
// NO cross-section reads (round-6's bug). NO cooperative launch (round-7's
// bug: coop launch does not execute under the harness's graph capture).
// ---------------------------------------------------------------------------
__global__ __launch_bounds__(256) void fused_front_kernel(
    const float* __restrict__ valW, const float* __restrict__ Wih,
    const float* __restrict__ Whh, float* __restrict__ Wbig,
    const float* __restrict__ qW, const float* __restrict__ qb,
    const float* __restrict__ keyW, const float* __restrict__ keyb,
    const float* __restrict__ valb,
    float* __restrict__ Wq, float* __restrict__ qoffW,
    float* __restrict__ cqk, float* __restrict__ cqoff,
    float* __restrict__ bvec,
    const int* __restrict__ dst, int* __restrict__ blockhist)
{
    __shared__ int h[N_PART];   // used only by block_hist section
    int blk = blockIdx.x;
    int t = threadIdx.x;

    if (blk < 512) {
        // ---- build_wbig ----
        int idx = blk * 256 + t;   // 131072 total
        int k = idx >> 9;
        int jn = idx & 511;
        int j = (jn & 3) * 128 + (jn >> 2);
        float v = 0.f;
        if (k < 128) {
            if (j < 384) {
                float acc = 0.f;
                #pragma unroll 8
                for (int m = 0; m < 128; m++)
                    acc += valW[k * 128 + m] * Wih[j * 128 + m];
                v = acc;
            }
        } else {
            int kp = k - 128;
            if (j < 256)       v = Whh[j * 128 + kp];
            else if (j >= 384) v = Whh[(j - 128) * 128 + kp];
        }
        Wbig[k * 512 + jn] = v;
    } else if (blk < 644) {
        // ---- build_small ----
        int jx = (blk - 512) * 256 + t;
        if (jx < 32768) {
            int k = jx >> 7, j = jx & 127;
            float acc = 0.f;
            #pragma unroll
            for (int a = 0; a < D_ATT; a++) acc += qW[k * D_ATT + a] * keyW[j * D_ATT + a];
            Wq[k * 128 + j] = acc;
        } else if (jx < 33024) {
            int k = jx - 32768;
            float acc = 0.f;
            #pragma unroll
            for (int a = 0; a < D_ATT; a++) acc += qW[k * D_ATT + a] * keyb[a];
            qoffW[k] = acc;
        } else if (jx < 33152) {
            int j = jx - 33024;
            float acc = 0.f;
            #pragma unroll
            for (int a = 0; a < D_ATT; a++) acc += keyW[j * D_ATT + a] * qb[a];
            cqk[j] = acc;
        } else if (jx == 33152) {
            float acc = 0.f;
            #pragma unroll
            for (int a = 0; a < D_ATT; a++) acc += keyb[a] * qb[a];
            cqoff[0] = acc;
        } else if (jx >= 33280 && jx < 33664) {
            int c = jx - 33280;
            float acc = 0.f;
            #pragma unroll 8
            for (int m = 0; m < 128; m++) acc += valb[m] * Wih[c * 128 + m];
            bvec[c] = acc;
        }
    } else {
        // ---- block_hist ----
        int b = blk - 644;
        for (int i = t; i < N_PART; i += 256) h[i] = 0;
        __syncthreads();
        int beg = b * EPB, end = min(beg + EPB, N_EDGES);
        for (int e = beg + t; e < end; e += 256)
            atomicAdd(&h[dst[e]], 1);
        __syncthreads();
        for (int i = t; i < N_PART; i += 256)
            blockhist[(size_t)b * N_PART + i] = h[i];
    }
}

// ---------------------------------------------------------------------------
// L2 — colscan ∥ query_gemm (645 blocks). Disjoint sets: colscan rw
// {blockhist,totals}; query reads {ph,gr,Wq,qoffW,cqk,cqoff} (all from L1 or
// inputs), writes {qk,qoff}. Both depend only on L1 -> safe in one launch.
//   [0,20):   colscan — per-dst column scan over blocks
//   [20,645): query_gemm — qk[5000][128], qoff[5000]
// ---------------------------------------------------------------------------
__global__ __launch_bounds__(256) void colscan_query_kernel(
    int* __restrict__ blockhist, int* __restrict__ totals,
    const float* __restrict__ ph, const float* __restrict__ gr,
    const float* __restrict__ Wq, const float* __restrict__ qoffW,
    const float* __restrict__ cqk, const float* __restrict__ cqoff,
    float* __restrict__ qk, float* __restrict__ qoff)
{
    __shared__ float s_in[TPV6][256];   // query section only (8192 B)
    int blk = blockIdx.x;
    int t = threadIdx.x;

    if (blk < 20) {
        // ---- colscan ----
        int i = blk * 256 + t;
        if (i >= N_PART) return;
        int run = 0;
        for (int b = 0; b < NBLK; b++) {
            size_t idx = (size_t)b * N_PART + i;
            int v = blockhist[idx];
            blockhist[idx] = run;
            run += v;
        }
        totals[i] = run;
    } else {
        // ---- query_gemm (verified round 5) ----
        int pbase = (blk - 20) * TPV6;

        for (int f = t; f < TPV6 * 64; f += 256) {
            int pl = f >> 6, r = f & 63;
            int c4 = r * 4;
            int p = pbase + pl;
            float4 v;
            if (c4 < 128) v = *(const float4*)(ph + (size_t)p * 128 + c4);
            else          v = *(const float4*)(gr + (size_t)p * 128 + (c4 - 128));
            *(float4*)&s_in[pl][c4] = v;
        }
        __syncthreads();

        int cq = (t & 31) * 4;   // column quad
        int pl = t >> 5;         // particle 0..7
        const float* wp = Wq + cq;

        float4 acc = {0.f, 0.f, 0.f, 0.f};
        float4 wa0 = *(const float4*)(wp);
        float4 wa1 = *(const float4*)(wp + 128);
        float4 wa2 = *(const float4*)(wp + 256);
        float4 wa3 = *(const float4*)(wp + 384);
        float4 xa  = *(const float4*)&s_in[pl][0];
        float4 wb0 = *(const float4*)(wp + 512);
        float4 wb1 = *(const float4*)(wp + 640);
        float4 wb2 = *(const float4*)(wp + 768);
        float4 wb3 = *(const float4*)(wp + 896);
        float4 xb  = *(const float4*)&s_in[pl][4];

        for (int k = 0; k < 256; k += 8) {
            float4 ca0 = wa0, ca1 = wa1, ca2 = wa2, ca3 = wa3, cxa = xa;
            if (k + 8 < 256) {
                const float* wn = wp + (size_t)(k + 8) * 128;
                wa0 = *(const float4*)(wn);
                wa1 = *(const float4*)(wn + 128);
                wa2 = *(const float4*)(wn + 256);
                wa3 = *(const float4*)(wn + 384);
                xa  = *(const float4*)&s_in[pl][k + 8];
            }
            q_body(acc, ca0, ca1, ca2, ca3, cxa);
            float4 cb0 = wb0, cb1 = wb1, cb2 = wb2, cb3 = wb3, cxb = xb;
            if (k + 12 < 256) {
                const float* wn = wp + (size_t)(k + 12) * 128;
                wb0 = *(const float4*)(wn);
                wb1 = *(const float4*)(wn + 128);
                wb2 = *(const float4*)(wn + 256);
                wb3 = *(const float4*)(wn + 384);
                xb  = *(const float4*)&s_in[pl][k + 12];
            }
            q_body(acc, cb0, cb1, cb2, cb3, cxb);
        }

        float4 cst = *(const float4*)(cqk + cq);
        float4 o;
        o.x = cst.x + acc.x; o.y = cst.y + acc.y;
        o.z = cst.z + acc.z; o.w = cst.w + acc.w;
        *(float4*)(qk + (size_t)(pbase + pl) * 128 + cq) = o;

        // qoff: wave wv handles particles 2*wv, 2*wv+1
        int wv = t >> 6, l = t & 63;
        float co = cqoff[0];
        #pragma unroll
        for (int i = 0; i < 2; i++) {
            int pp = wv * 2 + i;
            float s = s_in[pp][l]       * qoffW[l]
                    + s_in[pp][l + 64]  * qoffW[l + 64]
                    + s_in[pp][l + 128] * qoffW[l + 128]
                    + s_in[pp][l + 192] * qoffW[l + 192];
            #pragma unroll
            for (int off = 1; off <= 32; off <<= 1) s += __shfl_xor(s, off, 64);
            if (l == 0) qoff[pbase + pp] = co + s;
        }
    }
}

// ---------------------------------------------------------------------------
// L3: exclusive scan of totals[5000] -> offsets[5001] (verified)
// ---------------------------------------------------------------------------
__global__ __launch_bounds__(256) void scan_kernel(
    const int* __restrict__ totals, int* __restrict__ offsets)
{
    __shared__ int ss[256];
    int t = threadIdx.x;
    const int CH = 20;
    int beg = t * CH;
    int end = min(beg + CH, N_PART);
    int lsum = 0;
    for (int i = beg; i < end; i++) lsum += totals[i];
    ss[t] = lsum;
    __syncthreads();
    for (int off = 1; off < 256; off <<= 1) {
        int v = (t >= off) ? ss[t - off] : 0;
        __syncthreads();
        ss[t] += v;
        __syncthreads();
    }
    int base = ss[t] - lsum;
    for (int i = beg; i < end; i++) {
        offsets[i] = base;
        base += totals[i];
    }
    if (t == 0) offsets[N_PART] = N_EDGES;
}

// ---------------------------------------------------------------------------
// L4: scatter src into dst-sorted order using per-block LDS cursors (verified)
// ---------------------------------------------------------------------------
__global__ __launch_bounds__(256) void scatter_sorted_kernel(
    const int* __restrict__ src, const int* __restrict__ dst,
    const int* __restrict__ offsets, const int* __restrict__ blockhist,
    int* __restrict__ ssrc)
{
    __shared__ int cur[N_PART];
    int b = blockIdx.x;
    for (int i = threadIdx.x; i < N_PART; i += 256)
        cur[i] = offsets[i] + blockhist[(size_t)b * N_PART + i];
    __syncthreads();
    int beg = b * EPB, end = min(beg + EPB, N_EDGES);
    for (int e = beg + threadIdx.x; e < end; e += 256) {
        int d = dst[e];
        int pos = atomicAdd(&cur[d], 1);
        ssrc[pos] = src[e];
    }
}

// ---------------------------------------------------------------------------
// L5: per-dst edge accumulation. Half-wave (32 lanes x float4) per edge.
// Round-0 form (gather-service-bound; stable 72us / 3.35TB/s across rounds).
// ---------------------------------------------------------------------------
__global__ __launch_bounds__(256) void edge_agg_kernel(
    const float* __restrict__ nodes, const float* __restrict__ qk,
    const float* __restrict__ qoff,
    const int* __restrict__ offsets, const int* __restrict__ ssrc,
    float* __restrict__ agg, float* __restrict__ att_sum)
{
    const float norm = 0.22360679774997896f;  // 1/sqrt(20)
    int p = blockIdx.x;
    int tid = threadIdx.x;
    int lane = tid & 63;
    int wave = tid >> 6;
    int half = lane >> 5;
    int colq = (lane & 31) * 4;

    const float4 q = *(const float4*)(qk + (size_t)p * 128 + colq);
    float qo = qoff[p];
    int beg = offsets[p], end = offsets[p + 1];
    int n = end - beg;
    int np = (n + 1) >> 1;   // total pairs (last may be partial)
    int npfull = n >> 1;     // pairs with both edges present

    float4 a = {0.f, 0.f, 0.f, 0.f};
    float asum = 0.f;

    int pi = wave;
    for (; pi + 12 < npfull; pi += 16) {
        int e0 = beg + 2 * pi + half;
        int s0 = ssrc[e0];
        int s1 = ssrc[e0 + 8];
        int s2 = ssrc[e0 + 16];
        int s3 = ssrc[e0 + 24];
        float4 x0 = *(const float4*)(nodes + (size_t)s0 * 128 + colq);
        float4 x1 = *(const float4*)(nodes + (size_t)s1 * 128 + colq);
        float4 x2 = *(const float4*)(nodes + (size_t)s2 * 128 + colq);
        float4 x3 = *(const float4*)(nodes + (size_t)s3 * 128 + colq);
        float d0 = x0.x * q.x + x0.y * q.y + x0.z * q.z + x0.w * q.w;
        float d1 = x1.x * q.x + x1.y * q.y + x1.z * q.z + x1.w * q.w;
        float d2 = x2.x * q.x + x2.y * q.y + x2.z * q.z + x2.w * q.w;
        float d3 = x3.x * q.x + x3.y * q.y + x3.z * q.z + x3.w * q.w;
        #pragma unroll
        for (int off = 1; off <= 16; off <<= 1) {
            d0 += __shfl_xor(d0, off, 64);
            d1 += __shfl_xor(d1, off, 64);
            d2 += __shfl_xor(d2, off, 64);
            d3 += __shfl_xor(d3, off, 64);
        }
        float t0 = (d0 + qo) * norm;
        float t1 = (d1 + qo) * norm;
        float t2 = (d2 + qo) * norm;
        float t3 = (d3 + qo) * norm;
        a.x += t0 * x0.x + t1 * x1.x + t2 * x2.x + t3 * x3.x;
        a.y += t0 * x0.y + t1 * x1.y + t2 * x2.y + t3 * x3.y;
        a.z += t0 * x0.z + t1 * x1.z + t2 * x2.z + t3 * x3.z;
        a.w += t0 * x0.w + t1 * x1.w + t2 * x2.w + t3 * x3.w;
        asum += t0 + t1 + t2 + t3;
    }
    for (; pi < np; pi += 4) {
        int e0 = beg + 2 * pi;
        bool has1 = (e0 + 1 < end);
        int s0 = ssrc[e0];
        int s1 = has1 ? ssrc[e0 + 1] : s0;
        int s = half ? s1 : s0;
        float4 x = *(const float4*)(nodes + (size_t)s * 128 + colq);
        float d = x.x * q.x + x.y * q.y + x.z * q.z + x.w * q.w;
        #pragma unroll
        for (int off = 1; off <= 16; off <<= 1) d += __shfl_xor(d, off, 64);
        float att = (d + qo) * norm;
        if (half && !has1) att = 0.f;
        a.x += att * x.x; a.y += att * x.y; a.z += att * x.z; a.w += att * x.w;
        asum += att;
    }

    a.x += __shfl_xor(a.x, 32, 64);
    a.y += __shfl_xor(a.y, 32, 64);
    a.z += __shfl_xor(a.z, 32, 64);
    a.w += __shfl_xor(a.w, 32, 64);
    asum += __shfl_xor(asum, 32, 64);

    __shared__ float s_acc[4][128];
    __shared__ float s_as[4];
    if (lane < 32) {
        *(float4*)&s_acc[wave][colq] = a;
        if (lane == 0) s_as[wave] = asum;
    }
    __syncthreads();

    if (tid < 128) {
        float v = s_acc[0][tid] + s_acc[1][tid] + s_acc[2][tid] + s_acc[3][tid];
        agg[(size_t)p * 128 + tid] = v;
        if (tid == 0) att_sum[p] = s_as[0] + s_as[1] + s_as[2] + s_as[3];
    }
}

// ---------------------------------------------------------------------------
// L6: K4 v6 (round-4 measured-good config): single K=256 GEMM
// G = [agg|h] @ Wbig_interleaved (+bias/asum*bvec), gates in registers,
// LayerNorm + MLP + residual. Barrier-free K-loop, w direct from L2-resident
// global, 1-body-deep register prefetch. TPV6=8, 625 blocks.
// ---------------------------------------------------------------------------
__global__ __launch_bounds__(256) void gru_fused_v6(
    const float* __restrict__ agg, const float* __restrict__ att_sum,
    const float* __restrict__ ph,
    const float* __restrict__ Wbig, const float* __restrict__ bvec,
    const float* __restrict__ bih, const float* __restrict__ bhh,
    const float* __restrict__ lng, const float* __restrict__ lnb,
    const float* __restrict__ W1, const float* __restrict__ b1,
    const float* __restrict__ W2, const float* __restrict__ b2,
    float* __restrict__ out)
{
    __shared__ float s_in[TPV6][256];    // [agg | h] per particle (8192 B)
    __shared__ float s_ln[TPV6][128];    //                        (4096 B)
    __shared__ float s_hid[TPV6][64];    //                        (2048 B)

    int t = threadIdx.x;
    int pbase = blockIdx.x * TPV6;

    for (int f = t; f < TPV6 * 64; f += 256) {
        int pl = f >> 6, r = f & 63;
        int c4 = r * 4;
        int p = pbase + pl;
        float4 v;
        if (c4 < 128) v = *(const float4*)(agg + (size_t)p * 128 + c4);
        else          v = *(const float4*)(ph + (size_t)p * 128 + (c4 - 128));
        *(float4*)&s_in[pl][c4] = v;
    }

    int c  = t & 127;        // output column 0..127
    int j4 = c * 4;          // interleaved column base in Wbig
    int pg = t >> 7;         // particle group 0/1 -> particles pg*4 .. pg*4+3
    float4 cb, bv;
    cb.x = bih[c]       + bhh[c];        bv.x = bvec[c];        // r
    cb.y = bih[128 + c] + bhh[128 + c];  bv.y = bvec[128 + c];  // z
    cb.z = bih[256 + c];                 bv.z = bvec[256 + c];  // i_n
    cb.w = bhh[256 + c];                 bv.w = 0.f;            // h_n
    float4 acc[4];
    #pragma unroll
    for (int i = 0; i < 4; i++) {
        float as = att_sum[pbase + pg * 4 + i];
        acc[i].x = cb.x + as * bv.x;
        acc[i].y = cb.y + as * bv.y;
        acc[i].z = cb.z + as * bv.z;
        acc[i].w = cb.w + as * bv.w;
    }
    __syncthreads();

    // ---- K-loop: barrier-free, 1-body-deep prefetch
    const float* wp = Wbig + j4;
    float4 w0 = *(const float4*)(wp);
    float4 w1 = *(const float4*)(wp + 512);
    float4 w2 = *(const float4*)(wp + 1024);
    float4 w3 = *(const float4*)(wp + 1536);
    float4 x0 = *(const float4*)&s_in[pg * 4 + 0][0];
    float4 x1 = *(const float4*)&s_in[pg * 4 + 1][0];
    float4 x2 = *(const float4*)&s_in[pg * 4 + 2][0];
    float4 x3 = *(const float4*)&s_in[pg * 4 + 3][0];
    for (int k = 0; k < 256; k += 4) {
        float4 cw0 = w0, cw1 = w1, cw2 = w2, cw3 = w3;
        float4 cx0 = x0, cx1 = x1, cx2 = x2, cx3 = x3;
        if (k < 252) {
            const float* wn = wp + (size_t)(k + 4) * 512;
            w0 = *(const float4*)(wn);
            w1 = *(const float4*)(wn + 512);
            w2 = *(const float4*)(wn + 1024);
            w3 = *(const float4*)(wn + 1536);
            x0 = *(const float4*)&s_in[pg * 4 + 0][k + 4];
            x1 = *(const float4*)&s_in[pg * 4 + 1][k + 4];
            x2 = *(const float4*)&s_in[pg * 4 + 2][k + 4];
            x3 = *(const float4*)&s_in[pg * 4 + 3][k + 4];
        }
        gru_body(acc, cw0, cw1, cw2, cw3, cx0, cx1, cx2, cx3);
    }

    // ---- gates entirely in registers: hn = (1-z)*n + z*h
    #pragma unroll
    for (int i = 0; i < 4; i++) {
        int pl = pg * 4 + i;
        float r = sigmoid_(acc[i].x);
        float z = sigmoid_(acc[i].y);
        float n = tanh_(acc[i].z + r * acc[i].w);
        float h = s_in[pl][128 + c];
        s_ln[pl][c] = (1.f - z) * n + z * h;
    }
    __syncthreads();

    // ---- LayerNorm per particle
    {
        int wv = t >> 6, l = t & 63;
        for (int pl = wv; pl < TPV6; pl += 4) {
            float v0 = s_ln[pl][l * 2], v1 = s_ln[pl][l * 2 + 1];
            float sum = v0 + v1, sq = v0 * v0 + v1 * v1;
            #pragma unroll
            for (int off = 1; off <= 32; off <<= 1) {
                sum += __shfl_xor(sum, off, 64);
                sq  += __shfl_xor(sq, off, 64);
            }
            float mu = sum * (1.f / 128.f);
            float var = sq * (1.f / 128.f) - mu * mu;
            float rstd = rsqrtf(var + 1e-5f);
            s_ln[pl][l * 2]     = (v0 - mu) * rstd * lng[l * 2] + lnb[l * 2];
            s_ln[pl][l * 2 + 1] = (v1 - mu) * rstd * lng[l * 2 + 1] + lnb[l * 2 + 1];
        }
    }
    __syncthreads();

    // ---- MLP hidden (8*64 = 512 outputs)
    for (int idx = t; idx < TPV6 * 64; idx += 256) {
        int pl = idx >> 6, u = idx & 63;
        float a0 = b1[u];
        #pragma unroll 4
        for (int k = 0; k < 128; k++) a0 += s_ln[pl][k] * W1[k * 64 + u];
        s_hid[pl][u] = fmaxf(a0, 0.f);
    }
    __syncthreads();

    // ---- MLP out + residual (256 column-quads)
    for (int idx = t; idx < TPV6 * 32; idx += 256) {
        int pl = idx >> 5, qd = idx & 31;
        int c4 = qd * 4;
        float4 o = *(const float4*)(b2 + c4);
        #pragma unroll 4
        for (int u = 0; u < 64; u++) {
            float av = s_hid[pl][u];
            float4 w = *(const float4*)(W2 + u * 128 + c4);
            o.x += av * w.x; o.y += av * w.y; o.z += av * w.z; o.w += av * w.w;
        }
        float4 h4 = *(const float4*)&s_in[pl][128 + c4];
        float4 res;
        res.x = h4.x + o.x; res.y = h4.y + o.y;
        res.z = h4.z + o.z; res.w = h4.w + o.w;
        *(float4*)(out + (size_t)(pbase + pl) * 128 + c4) = res;
    }
}

// ---------------------------------------------------------------------------
extern "C" void kernel_launch(void* const* d_in, const int* in_sizes, int n_in,
                              void* d_out, int out_size, void* d_ws, size_t ws_size,
                              hipStream_t stream) {
    const float* nodes = (const float*)d_in[0];
    const float* ph    = (const float*)d_in[1];
    const float* gr    = (const float*)d_in[2];
    const int*   src   = (const int*)d_in[3];
    const int*   dst   = (const int*)d_in[4];
    const float* keyW  = (const float*)d_in[5];
    const float* keyb  = (const float*)d_in[6];
    const float* valW  = (const float*)d_in[7];
    const float* valb  = (const float*)d_in[8];
    const float* qW    = (const float*)d_in[9];
    const float* qb    = (const float*)d_in[10];
    const float* Wih   = (const float*)d_in[11];
    const float* Whh   = (const float*)d_in[12];
    const float* bih   = (const float*)d_in[13];
    const float* bhh   = (const float*)d_in[14];
    const float* lng   = (const float*)d_in[15];
    const float* lnb   = (const float*)d_in[16];
    const float* W1    = (const float*)d_in[17];
    const float* b1    = (const float*)d_in[18];
    const float* W2    = (const float*)d_in[19];
    const float* b2    = (const float*)d_in[20];
    float* out = (float*)d_out;

    // workspace layout
    float* ws_f      = (float*)d_ws;
    float* qk        = ws_f;                     // 640,000
    float* qoff      = qk + 640000;              // 5,008
    float* agg       = qoff + 5008;              // 640,000
    float* att_sum   = agg + 640000;             // 5,008
    int*   totals    = (int*)(att_sum + 5008);   // 5,008
    int*   offsets   = totals + 5008;            // 5,008
    int*   blockhist = offsets + 5008;           // NBLK*5000
    int*   ssrc      = blockhist + (size_t)NBLK * N_PART;  // 1,000,000
    float* Wbig      = (float*)(ssrc + 1000000); // 131,072
    float* bvec      = Wbig + 131072;            // 512 (384 used)
    float* Wq        = bvec + 512;               // 32,768
    float* qoffW     = Wq + 32768;               // 256
    float* cqk       = qoffW + 256;              // 128
    float* cqoff     = cqk + 128;                // 16

    // L1: fused front (build_wbig | build_small | block_hist), 772 blocks.
    fused_front_kernel<<<772, 256, 0, stream>>>(
        valW, Wih, Whh, Wbig,
        qW, qb, keyW, keyb, valb,
        Wq, qoffW, cqk, cqoff, bvec,
        dst, blockhist);

    // L2: colscan | query_gemm, 645 blocks (both depend only on L1).
    colscan_query_kernel<<<20 + QBLKS, 256, 0, stream>>>(
        blockhist, totals, ph, gr, Wq, qoffW, cqk, cqoff, qk, qoff);

    // L3: exclusive scan (1 block).
    scan_kernel<<<1, 256, 0, stream>>>(totals, offsets);

    // L4: scatter (128 blocks).
    scatter_sorted_kernel<<<NBLK, 256, 0, stream>>>(src, dst, offsets, blockhist, ssrc);

    // L5: edge aggregation (gather-service-bound, stable 72us).
    edge_agg_kernel<<<N_PART, 256, 0, stream>>>(nodes, qk, qoff, offsets, ssrc, agg, att_sum);

    // L6: GRU + LN + MLP + residual (round-4 v6 config).
    gru_fused_v6<<<N_PART / TPV6, 256, 0, stream>>>(
        agg, att_sum, ph, Wbig, bvec, bih, bhh, lng, lnb, W1, b1, W2, b2, out);
}

// Round 9
// 280.633 us; speedup vs baseline: 1.1389x; 1.0522x over previous
//
#include <hip/hip_runtime.h>
#include <math.h>

#define N_NODES 100000
#define N_PART  5000
#define N_EDGES 1000000
#define D_NODE  128
#define D_PART  128
#define D_ATT   20
#define NBLK    128   // counting-sort blocks
#define EPB     ((N_EDGES + NBLK - 1) / NBLK)
#define TPV6    8     // particles per block in gru_fused_v6 / query path
#define QBLKS   (N_PART / TPV6)   // 625 query blocks

__device__ __forceinline__ float sigmoid_(float x) { return 1.f / (1.f + __expf(-x)); }
__device__ __forceinline__ float tanh_(float x)    { return 1.f - 2.f / (__expf(2.f * x) + 1.f); }

// 16-FMA body for the 512-wide GRU GEMM (4 k-rows x 4 cols x 4 particles)
__device__ __forceinline__ void gru_body(float4 acc[4],
    float4 w0, float4 w1, float4 w2, float4 w3,
    float4 x0, float4 x1, float4 x2, float4 x3)
{
    acc[0].x += x0.x * w0.x + x0.y * w1.x + x0.z * w2.x + x0.w * w3.x;
    acc[0].y += x0.x * w0.y + x0.y * w1.y + x0.z * w2.y + x0.w * w3.y;
    acc[0].z += x0.x * w0.z + x0.y * w1.z + x0.z * w2.z + x0.w * w3.z;
    acc[0].w += x0.x * w0.w + x0.y * w1.w + x0.z * w2.w + x0.w * w3.w;
    acc[1].x += x1.x * w0.x + x1.y * w1.x + x1.z * w2.x + x1.w * w3.x;
    acc[1].y += x1.x * w0.y + x1.y * w1.y + x1.z * w2.y + x1.w * w3.y;
    acc[1].z += x1.x * w0.z + x1.y * w1.z + x1.z * w2.z + x1.w * w3.z;
    acc[1].w += x1.x * w0.w + x1.y * w1.w + x1.z * w2.w + x1.w * w3.w;
    acc[2].x += x2.x * w0.x + x2.y * w1.x + x2.z * w2.x + x2.w * w3.x;
    acc[2].y += x2.x * w0.y + x2.y * w1.y + x2.z * w2.y + x2.w * w3.y;
    acc[2].z += x2.x * w0.z + x2.y * w1.z + x2.z * w2.z + x2.w * w3.z;
    acc[2].w += x2.x * w0.w + x2.y * w1.w + x2.z * w2.w + x2.w * w3.w;
    acc[3].x += x3.x * w0.x + x3.y * w1.x + x3.z * w2.x + x3.w * w3.x;
    acc[3].y += x3.x * w0.y + x3.y * w1.y + x3.z * w2.y + x3.w * w3.y;
    acc[3].z += x3.x * w0.z + x3.y * w1.z + x3.z * w2.z + x3.w * w3.z;
    acc[3].w += x3.x * w0.w + x3.y * w1.w + x3.z * w2.w + x3.w * w3.w;
}

// ---------------------------------------------------------------------------
// L1 — fused front-end (1267 blocks). FOUR disjoint sections — none reads
// another's output; every input comes from kernel arguments:
//   [0,512):     build_wbig — Wbig[256][512], gate-interleaved
//   [512,514):   bvec[c] = valb . Wih[c]   (c < 384)
//   [514,642):   block_hist — per-block LDS histogram of dst
//   [642,1267):  query two-stage (rank-20):
//                  query[p][a] = qb[a] + [ph|gr][p] . qW[:,a]   (LDS/L1 only)
//                  qk[p][j]    = query[p] . keyW[j]
//                  qoff[p]     = query[p] . keyb
//                Replaces the K=256 folded GEMM whose 64 serial L2-load
//                batches made it ~as slow as the whole GRU kernel.
// Shared pool = 20000 B (hist) unioned with query's 19968 B. 8 blocks/CU.
// ---------------------------------------------------------------------------
__global__ __launch_bounds__(256) void fused_front_kernel(
    const float* __restrict__ valW, const float* __restrict__ Wih,
    const float* __restrict__ Whh, float* __restrict__ Wbig,
    const float* __restrict__ valb, float* __restrict__ bvec,
    const int* __restrict__ dst, int* __restrict__ blockhist,
    const float* __restrict__ ph, const float* __restrict__ gr,
    const float* __restrict__ qW, const float* __restrict__ qb,
    const float* __restrict__ keyW, const float* __restrict__ keyb,
    float* __restrict__ qk, float* __restrict__ qoff)
{
    __shared__ float pool[5000];   // 20000 B unioned
    int blk = blockIdx.x;
    int t = threadIdx.x;

    if (blk < 512) {
        // ---- build_wbig (verified rounds 2-8) ----
        int idx = blk * 256 + t;   // 131072 total
        int k = idx >> 9;
        int jn = idx & 511;
        int j = (jn & 3) * 128 + (jn >> 2);
        float v = 0.f;
        if (k < 128) {
            if (j < 384) {
                float acc = 0.f;
                #pragma unroll 8
                for (int m = 0; m < 128; m++)
                    acc += valW[k * 128 + m] * Wih[j * 128 + m];
                v = acc;
            }
        } else {
            int kp = k - 128;
            if (j < 256)       v = Whh[j * 128 + kp];
            else if (j >= 384) v = Whh[(j - 128) * 128 + kp];
        }
        Wbig[k * 512 + jn] = v;
    } else if (blk < 514) {
        // ---- bvec (verified) ----
        int c = (blk - 512) * 256 + t;
        if (c < 384) {
            float acc = 0.f;
            #pragma unroll 8
            for (int m = 0; m < 128; m++) acc += valb[m] * Wih[c * 128 + m];
            bvec[c] = acc;
        }
    } else if (blk < 642) {
        // ---- block_hist (verified) ----
        int b = blk - 514;
        int* h = (int*)pool;
        for (int i = t; i < N_PART; i += 256) h[i] = 0;
        __syncthreads();
        int beg = b * EPB, end = min(beg + EPB, N_EDGES);
        for (int e = beg + t; e < end; e += 256)
            atomicAdd(&h[dst[e]], 1);
        __syncthreads();
        for (int i = t; i < N_PART; i += 256)
            blockhist[(size_t)b * N_PART + i] = h[i];
    } else {
        // ---- query two-stage (rank-20, LDS-resident) ----
        // pool layout (floats): s_in[8][260] @0 (2080, +4 pad kills 4-way
        // bank conflict on column reads), s_q[8][20] @2080 (160),
        // s_kw[128][21] @2240 (2688, pad 21), s_kb @4928 (20), s_qb @4948 (20)
        float (*s_in)[260] = (float (*)[260])pool;
        float (*s_q)[20]   = (float (*)[20])(pool + 2080);
        float (*s_kw)[21]  = (float (*)[21])(pool + 2240);
        float* s_kb = pool + 4928;
        float* s_qb = pool + 4948;

        int pbase = (blk - 642) * TPV6;

        // load inputs: 8 particles x 256 floats (rows padded to 260; row
        // byte-stride 1040 is 16B-aligned so float4 stores stay aligned)
        for (int f = t; f < TPV6 * 64; f += 256) {
            int pl = f >> 6, r = f & 63;
            int c4 = r * 4;
            int p = pbase + pl;
            float4 v;
            if (c4 < 128) v = *(const float4*)(ph + (size_t)p * 128 + c4);
            else          v = *(const float4*)(gr + (size_t)p * 128 + (c4 - 128));
            *(float4*)&s_in[pl][c4] = v;
        }
        // stage keyW [128][20] -> s_kw [128][21]
        for (int f = t; f < 2560; f += 256) {
            int j = f / 20, a = f - j * 20;
            s_kw[j][a] = keyW[f];
        }
        if (t < 20) { s_kb[t] = keyb[t]; s_qb[t] = qb[t]; }
        __syncthreads();

        // phase 1: query[pl][a], 160 outputs. s_in read is 4-addr/wave
        // (pad-broken banks -> conflict-free); qW read is wave-broadcast
        // coalesced (20 distinct addrs spanning 2 lines). No latency chain:
        // loads independent, unroll 8 keeps 8 in flight.
        if (t < 160) {
            int pl = t / 20, a = t - (t / 20) * 20;
            float acc = s_qb[a];
            const float* qwp = qW + a;
            #pragma unroll 8
            for (int k = 0; k < 256; k++) acc += s_in[pl][k] * qwp[k * 20];
            s_q[pl][a] = acc;
        }
        __syncthreads();

        // phase 2: qk[p][j0..j0+3] (20-dots from LDS), qoff
        {
            int pl = t >> 5, j0 = (t & 31) * 4;
            float4 o;
            float acc0 = 0.f, acc1 = 0.f, acc2 = 0.f, acc3 = 0.f;
            #pragma unroll
            for (int a = 0; a < 20; a++) {
                float qv = s_q[pl][a];
                acc0 += qv * s_kw[j0][a];
                acc1 += qv * s_kw[j0 + 1][a];
                acc2 += qv * s_kw[j0 + 2][a];
                acc3 += qv * s_kw[j0 + 3][a];
            }
            o.x = acc0; o.y = acc1; o.z = acc2; o.w = acc3;
            *(float4*)(qk + (size_t)(pbase + pl) * 128 + j0) = o;

            if (t < TPV6) {
                float acc = 0.f;
                #pragma unroll
                for (int a = 0; a < 20; a++) acc += s_kb[a] * s_q[t][a];
                qoff[pbase + t] = acc;
            }
        }
    }
}

// ---------------------------------------------------------------------------
// L2: per-dst column scan over blocks (verified round 4 standalone form)
// ---------------------------------------------------------------------------
__global__ __launch_bounds__(256) void colscan_kernel(
    int* __restrict__ blockhist, int* __restrict__ totals)
{
    int i = blockIdx.x * 256 + threadIdx.x;
    if (i >= N_PART) return;
    int run = 0;
    for (int b = 0; b < NBLK; b++) {
        size_t idx = (size_t)b * N_PART + i;
        int v = blockhist[idx];
        blockhist[idx] = run;
        run += v;
    }
    totals[i] = run;
}

// ---------------------------------------------------------------------------
// L3: exclusive scan of totals[5000] -> offsets[5001] (verified)
// ---------------------------------------------------------------------------
__global__ __launch_bounds__(256) void scan_kernel(
    const int* __restrict__ totals, int* __restrict__ offsets)
{
    __shared__ int ss[256];
    int t = threadIdx.x;
    const int CH = 20;
    int beg = t * CH;
    int end = min(beg + CH, N_PART);
    int lsum = 0;
    for (int i = beg; i < end; i++) lsum += totals[i];
    ss[t] = lsum;
    __syncthreads();
    for (int off = 1; off < 256; off <<= 1) {
        int v = (t >= off) ? ss[t - off] : 0;
        __syncthreads();
        ss[t] += v;
        __syncthreads();
    }
    int base = ss[t] - lsum;
    for (int i = beg; i < end; i++) {
        offsets[i] = base;
        base += totals[i];
    }
    if (t == 0) offsets[N_PART] = N_EDGES;
}

// ---------------------------------------------------------------------------
// L4: scatter src into dst-sorted order using per-block LDS cursors (verified)
// ---------------------------------------------------------------------------
__global__ __launch_bounds__(256) void scatter_sorted_kernel(
    const int* __restrict__ src, const int* __restrict__ dst,
    const int* __restrict__ offsets, const int* __restrict__ blockhist,
    int* __restrict__ ssrc)
{
    __shared__ int cur[N_PART];
    int b = blockIdx.x;
    for (int i = threadIdx.x; i < N_PART; i += 256)
        cur[i] = offsets[i] + blockhist[(size_t)b * N_PART + i];
    __syncthreads();
    int beg = b * EPB, end = min(beg + EPB, N_EDGES);
    for (int e = beg + threadIdx.x; e < end; e += 256) {
        int d = dst[e];
        int pos = atomicAdd(&cur[d], 1);
        ssrc[pos] = src[e];
    }
}

// ---------------------------------------------------------------------------
// L5: per-dst edge accumulation. Half-wave (32 lanes x float4) per edge.
// Round-0 form (gather-service-bound; stable 72us / 3.35TB/s across rounds).
// ---------------------------------------------------------------------------
__global__ __launch_bounds__(256) void edge_agg_kernel(
    const float* __restrict__ nodes, const float* __restrict__ qk,
    const float* __restrict__ qoff,
    const int* __restrict__ offsets, const int* __restrict__ ssrc,
    float* __restrict__ agg, float* __restrict__ att_sum)
{
    const float norm = 0.22360679774997896f;  // 1/sqrt(20)
    int p = blockIdx.x;
    int tid = threadIdx.x;
    int lane = tid & 63;
    int wave = tid >> 6;
    int half = lane >> 5;
    int colq = (lane & 31) * 4;

    const float4 q = *(const float4*)(qk + (size_t)p * 128 + colq);
    float qo = qoff[p];
    int beg = offsets[p], end = offsets[p + 1];
    int n = end - beg;
    int np = (n + 1) >> 1;   // total pairs (last may be partial)
    int npfull = n >> 1;     // pairs with both edges present

    float4 a = {0.f, 0.f, 0.f, 0.f};
    float asum = 0.f;

    int pi = wave;
    for (; pi + 12 < npfull; pi += 16) {
        int e0 = beg + 2 * pi + half;
        int s0 = ssrc[e0];
        int s1 = ssrc[e0 + 8];
        int s2 = ssrc[e0 + 16];
        int s3 = ssrc[e0 + 24];
        float4 x0 = *(const float4*)(nodes + (size_t)s0 * 128 + colq);
        float4 x1 = *(const float4*)(nodes + (size_t)s1 * 128 + colq);
        float4 x2 = *(const float4*)(nodes + (size_t)s2 * 128 + colq);
        float4 x3 = *(const float4*)(nodes + (size_t)s3 * 128 + colq);
        float d0 = x0.x * q.x + x0.y * q.y + x0.z * q.z + x0.w * q.w;
        float d1 = x1.x * q.x + x1.y * q.y + x1.z * q.z + x1.w * q.w;
        float d2 = x2.x * q.x + x2.y * q.y + x2.z * q.z + x2.w * q.w;
        float d3 = x3.x * q.x + x3.y * q.y + x3.z * q.z + x3.w * q.w;
        #pragma unroll
        for (int off = 1; off <= 16; off <<= 1) {
            d0 += __shfl_xor(d0, off, 64);
            d1 += __shfl_xor(d1, off, 64);
            d2 += __shfl_xor(d2, off, 64);
            d3 += __shfl_xor(d3, off, 64);
        }
        float t0 = (d0 + qo) * norm;
        float t1 = (d1 + qo) * norm;
        float t2 = (d2 + qo) * norm;
        float t3 = (d3 + qo) * norm;
        a.x += t0 * x0.x + t1 * x1.x + t2 * x2.x + t3 * x3.x;
        a.y += t0 * x0.y + t1 * x1.y + t2 * x2.y + t3 * x3.y;
        a.z += t0 * x0.z + t1 * x1.z + t2 * x2.z + t3 * x3.z;
        a.w += t0 * x0.w + t1 * x1.w + t2 * x2.w + t3 * x3.w;
        asum += t0 + t1 + t2 + t3;
    }
    for (; pi < np; pi += 4) {
        int e0 = beg + 2 * pi;
        bool has1 = (e0 + 1 < end);
        int s0 = ssrc[e0];
        int s1 = has1 ? ssrc[e0 + 1] : s0;
        int s = half ? s1 : s0;
        float4 x = *(const float4*)(nodes + (size_t)s * 128 + colq);
        float d = x.x * q.x + x.y * q.y + x.z * q.z + x.w * q.w;
        #pragma unroll
        for (int off = 1; off <= 16; off <<= 1) d += __shfl_xor(d, off, 64);
        float att = (d + qo) * norm;
        if (half && !has1) att = 0.f;
        a.x += att * x.x; a.y += att * x.y; a.z += att * x.z; a.w += att * x.w;
        asum += att;
    }

    a.x += __shfl_xor(a.x, 32, 64);
    a.y += __shfl_xor(a.y, 32, 64);
    a.z += __shfl_xor(a.z, 32, 64);
    a.w += __shfl_xor(a.w, 32, 64);
    asum += __shfl_xor(asum, 32, 64);

    __shared__ float s_acc[4][128];
    __shared__ float s_as[4];
    if (lane < 32) {
        *(float4*)&s_acc[wave][colq] = a;
        if (lane == 0) s_as[wave] = asum;
    }
    __syncthreads();

    if (tid < 128) {
        float v = s_acc[0][tid] + s_acc[1][tid] + s_acc[2][tid] + s_acc[3][tid];
        agg[(size_t)p * 128 + tid] = v;
        if (tid == 0) att_sum[p] = s_as[0] + s_as[1] + s_as[2] + s_as[3];
    }
}

// ---------------------------------------------------------------------------
// L6: K4 v6 (round-4 measured-good config): single K=256 GEMM
// G = [agg|h] @ Wbig_interleaved (+bias/asum*bvec), gates in registers,
// LayerNorm + MLP + residual. Barrier-free K-loop, w direct from L2-resident
// global, 1-body-deep register prefetch. TPV6=8, 625 blocks.
// ---------------------------------------------------------------------------
__global__ __launch_bounds__(256) void gru_fused_v6(
    const float* __restrict__ agg, const float* __restrict__ att_sum,
    const float* __restrict__ ph,
    const float* __restrict__ Wbig, const float* __restrict__ bvec,
    const float* __restrict__ bih, const float* __restrict__ bhh,
    const float* __restrict__ lng, const float* __restrict__ lnb,
    const float* __restrict__ W1, const float* __restrict__ b1,
    const float* __restrict__ W2, const float* __restrict__ b2,
    float* __restrict__ out)
{
    __shared__ float s_in[TPV6][256];    // [agg | h] per particle (8192 B)
    __shared__ float s_ln[TPV6][128];    //                        (4096 B)
    __shared__ float s_hid[TPV6][64];    //                        (2048 B)

    int t = threadIdx.x;
    int pbase = blockIdx.x * TPV6;

    for (int f = t; f < TPV6 * 64; f += 256) {
        int pl = f >> 6, r = f & 63;
        int c4 = r * 4;
        int p = pbase + pl;
        float4 v;
        if (c4 < 128) v = *(const float4*)(agg + (size_t)p * 128 + c4);
        else          v = *(const float4*)(ph + (size_t)p * 128 + (c4 - 128));
        *(float4*)&s_in[pl][c4] = v;
    }

    int c  = t & 127;        // output column 0..127
    int j4 = c * 4;          // interleaved column base in Wbig
    int pg = t >> 7;         // particle group 0/1 -> particles pg*4 .. pg*4+3
    float4 cb, bv;
    cb.x = bih[c]       + bhh[c];        bv.x = bvec[c];        // r
    cb.y = bih[128 + c] + bhh[128 + c];  bv.y = bvec[128 + c];  // z
    cb.z = bih[256 + c];                 bv.z = bvec[256 + c];  // i_n
    cb.w = bhh[256 + c];                 bv.w = 0.f;            // h_n
    float4 acc[4];
    #pragma unroll
    for (int i = 0; i < 4; i++) {
        float as = att_sum[pbase + pg * 4 + i];
        acc[i].x = cb.x + as * bv.x;
        acc[i].y = cb.y + as * bv.y;
        acc[i].z = cb.z + as * bv.z;
        acc[i].w = cb.w + as * bv.w;
    }
    __syncthreads();

    // ---- K-loop: barrier-free, 1-body-deep prefetch
    const float* wp = Wbig + j4;
    float4 w0 = *(const float4*)(wp);
    float4 w1 = *(const float4*)(wp + 512);
    float4 w2 = *(const float4*)(wp + 1024);
    float4 w3 = *(const float4*)(wp + 1536);
    float4 x0 = *(const float4*)&s_in[pg * 4 + 0][0];
    float4 x1 = *(const float4*)&s_in[pg * 4 + 1][0];
    float4 x2 = *(const float4*)&s_in[pg * 4 + 2][0];
    float4 x3 = *(const float4*)&s_in[pg * 4 + 3][0];
    for (int k = 0; k < 256; k += 4) {
        float4 cw0 = w0, cw1 = w1, cw2 = w2, cw3 = w3;
        float4 cx0 = x0, cx1 = x1, cx2 = x2, cx3 = x3;
        if (k < 252) {
            const float* wn = wp + (size_t)(k + 4) * 512;
            w0 = *(const float4*)(wn);
            w1 = *(const float4*)(wn + 512);
            w2 = *(const float4*)(wn + 1024);
            w3 = *(const float4*)(wn + 1536);
            x0 = *(const float4*)&s_in[pg * 4 + 0][k + 4];
            x1 = *(const float4*)&s_in[pg * 4 + 1][k + 4];
            x2 = *(const float4*)&s_in[pg * 4 + 2][k + 4];
            x3 = *(const float4*)&s_in[pg * 4 + 3][k + 4];
        }
        gru_body(acc, cw0, cw1, cw2, cw3, cx0, cx1, cx2, cx3);
    }

    // ---- gates entirely in registers: hn = (1-z)*n + z*h
    #pragma unroll
    for (int i = 0; i < 4; i++) {
        int pl = pg * 4 + i;
        float r = sigmoid_(acc[i].x);
        float z = sigmoid_(acc[i].y);
        float n = tanh_(acc[i].z + r * acc[i].w);
        float h = s_in[pl][128 + c];
        s_ln[pl][c] = (1.f - z) * n + z * h;
    }
    __syncthreads();

    // ---- LayerNorm per particle
    {
        int wv = t >> 6, l = t & 63;
        for (int pl = wv; pl < TPV6; pl += 4) {
            float v0 = s_ln[pl][l * 2], v1 = s_ln[pl][l * 2 + 1];
            float sum = v0 + v1, sq = v0 * v0 + v1 * v1;
            #pragma unroll
            for (int off = 1; off <= 32; off <<= 1) {
                sum += __shfl_xor(sum, off, 64);
                sq  += __shfl_xor(sq, off, 64);
            }
            float mu = sum * (1.f / 128.f);
            float var = sq * (1.f / 128.f) - mu * mu;
            float rstd = rsqrtf(var + 1e-5f);
            s_ln[pl][l * 2]     = (v0 - mu) * rstd * lng[l * 2] + lnb[l * 2];
            s_ln[pl][l * 2 + 1] = (v1 - mu) * rstd * lng[l * 2 + 1] + lnb[l * 2 + 1];
        }
    }
    __syncthreads();

    // ---- MLP hidden (8*64 = 512 outputs)
    for (int idx = t; idx < TPV6 * 64; idx += 256) {
        int pl = idx >> 6, u = idx & 63;
        float a0 = b1[u];
        #pragma unroll 4
        for (int k = 0; k < 128; k++) a0 += s_ln[pl][k] * W1[k * 64 + u];
        s_hid[pl][u] = fmaxf(a0, 0.f);
    }
    __syncthreads();

    // ---- MLP out + residual (256 column-quads)
    for (int idx = t; idx < TPV6 * 32; idx += 256) {
        int pl = idx >> 5, qd = idx & 31;
        int c4 = qd * 4;
        float4 o = *(const float4*)(b2 + c4);
        #pragma unroll 4
        for (int u = 0; u < 64; u++) {
            float av = s_hid[pl][u];
            float4 w = *(const float4*)(W2 + u * 128 + c4);
            o.x += av * w.x; o.y += av * w.y; o.z += av * w.z; o.w += av * w.w;
        }
        float4 h4 = *(const float4*)&s_in[pl][128 + c4];
        float4 res;
        res.x = h4.x + o.x; res.y = h4.y + o.y;
        res.z = h4.z + o.z; res.w = h4.w + o.w;
        *(float4*)(out + (size_t)(pbase + pl) * 128 + c4) = res;
    }
}

// ---------------------------------------------------------------------------
extern "C" void kernel_launch(void* const* d_in, const int* in_sizes, int n_in,
                              void* d_out, int out_size, void* d_ws, size_t ws_size,
                              hipStream_t stream) {
    const float* nodes = (const float*)d_in[0];
    const float* ph    = (const float*)d_in[1];
    const float* gr    = (const float*)d_in[2];
    const int*   src   = (const int*)d_in[3];
    const int*   dst   = (const int*)d_in[4];
    const float* keyW  = (const float*)d_in[5];
    const float* keyb  = (const float*)d_in[6];
    const float* valW  = (const float*)d_in[7];
    const float* valb  = (const float*)d_in[8];
    const float* qW    = (const float*)d_in[9];
    const float* qb    = (const float*)d_in[10];
    const float* Wih   = (const float*)d_in[11];
    const float* Whh   = (const float*)d_in[12];
    const float* bih   = (const float*)d_in[13];
    const float* bhh   = (const float*)d_in[14];
    const float* lng   = (const float*)d_in[15];
    const float* lnb   = (const float*)d_in[16];
    const float* W1    = (const float*)d_in[17];
    const float* b1    = (const float*)d_in[18];
    const float* W2    = (const float*)d_in[19];
    const float* b2    = (const float*)d_in[20];
    float* out = (float*)d_out;

    // workspace layout
    float* ws_f      = (float*)d_ws;
    float* qk        = ws_f;                     // 640,000
    float* qoff      = qk + 640000;              // 5,008
    float* agg       = qoff + 5008;              // 640,000
    float* att_sum   = agg + 640000;             // 5,008
    int*   totals    = (int*)(att_sum + 5008);   // 5,008
    int*   offsets   = totals + 5008;            // 5,008
    int*   blockhist = offsets + 5008;           // NBLK*5000
    int*   ssrc      = blockhist + (size_t)NBLK * N_PART;  // 1,000,000
    float* Wbig      = (float*)(ssrc + 1000000); // 131,072
    float* bvec      = Wbig + 131072;            // 512 (384 used)

    // L1: fused front (build_wbig | bvec | block_hist | query two-stage),
    // 1267 blocks, all sections read only kernel inputs.
    fused_front_kernel<<<512 + 2 + NBLK + QBLKS, 256, 0, stream>>>(
        valW, Wih, Whh, Wbig,
        valb, bvec,
        dst, blockhist,
        ph, gr, qW, qb, keyW, keyb, qk, qoff);

    // L2: colscan (20 blocks; depends on blockhist from L1).
    colscan_kernel<<<(N_PART + 255) / 256, 256, 0, stream>>>(blockhist, totals);

    // L3: exclusive scan (1 block).
    scan_kernel<<<1, 256, 0, stream>>>(totals, offsets);

    // L4: scatter (128 blocks).
    scatter_sorted_kernel<<<NBLK, 256, 0, stream>>>(src, dst, offsets, blockhist, ssrc);

    // L5: edge aggregation (gather-service-bound, stable 72us).
    edge_agg_kernel<<<N_PART, 256, 0, stream>>>(nodes, qk, qoff, offsets, ssrc, agg, att_sum);

    // L6: GRU + LN + MLP + residual (round-4 v6 config).
    gru_fused_v6<<<N_PART / TPV6, 256, 0, stream>>>(
        agg, att_sum, ph, Wbig, bvec, bih, bhh, lng, lnb, W1, b1, W2, b2, out);
}